// Round 11
// baseline (228.545 us; speedup 1.0000x reference)
//
#include <hip/hip_runtime.h>

#define BB 16
#define NN 50
#define HH 128
#define VV 40000
#define VO 39999

typedef unsigned short u16;
typedef unsigned int u32;
typedef __attribute__((ext_vector_type(8))) short short8;
typedef __attribute__((ext_vector_type(4))) float f32x4;

// ---- workspace layout (float offsets) ---- high-water 673,808 f32 = 2.70 MB
#define OFF_HID    0          // 800*128
#define OFF_EIN    102400     // 800*128
#define OFF_EOUT   204800     // 800*128
#define OFF_QTBF   307200     // qt fragments: per b: 4tile x 4kc x 512 u16 = 16 KB
#define OFF_LEN    411648     // 16 ints
#define OFF_WIHT   411664     // 256*384 k-major
#define OFF_WHHT   509968     // 128*384
#define OFF_WEINT  559120     // 128*128
#define OFF_WEOUTT 575504
#define OFF_WTWOT  591888
#define OFF_WTT    608272
#define OFF_WONET  624656
#define OFF_WTRT   641040     // 256*128  -> ends 673808

__device__ __forceinline__ float sigm(float x){ return 1.0f/(1.0f+__expf(-x)); }
__device__ __forceinline__ float b2f(u16 u){
  union { u32 i; float f; } c; c.i = ((u32)u) << 16; return c.f;
}
__device__ __forceinline__ u16 f2b(float f){
  union { float f; u32 i; } c; c.f = f;
  u32 u = c.i;
  return (u16)((u + 0x7fffu + ((u >> 16) & 1u)) >> 16);
}
// u16 index into qt fragment store for element (b, n, k)
__device__ __forceinline__ int frag_idx(int b, int n, int k){
  int tile = n>>4, vlo = n&15, kc = k>>5, quad = (k>>3)&3, j = k&7;
  return (((b*4+tile)*4+kc)<<9) + ((quad<<4)+vlo)*8 + j;
}

// ---- merged: embedding gather + transpose all weights to k-major ----
__global__ void k_pre(const int* __restrict__ items, const float* __restrict__ emb,
                      const float* __restrict__ w_ih, const float* __restrict__ w_hh,
                      const float* __restrict__ W_ein, const float* __restrict__ W_eout,
                      const float* __restrict__ W_two, const float* __restrict__ W_t,
                      const float* __restrict__ W_one, const float* __restrict__ W_tr,
                      float* __restrict__ ws){
  int idx = blockIdx.x*256 + threadIdx.x;     // grid covers exactly 364544
  if (idx < 102400){
    int r = idx >> 7, h = idx & 127;
    ws[OFF_HID + idx] = emb[items[r]*128 + h];
  } else if (idx < 200704){
    int i = idx-102400; int k=i/384, j=i-k*384;
    ws[OFF_WIHT + i] = w_ih[j*256 + k];
  } else if (idx < 249856){
    int i = idx-200704; int k=i/384, j=i-k*384;
    ws[OFF_WHHT + i] = w_hh[j*128 + k];
  } else if (idx < 266240){
    int i = idx-249856; int k=i>>7, h=i&127;
    ws[OFF_WEINT + i] = W_ein[h*128 + k];
  } else if (idx < 282624){
    int i = idx-266240; int k=i>>7, h=i&127;
    ws[OFF_WEOUTT + i] = W_eout[h*128 + k];
  } else if (idx < 299008){
    int i = idx-282624; int k=i>>7, h=i&127;
    ws[OFF_WTWOT + i] = W_two[h*128 + k];
  } else if (idx < 315392){
    int i = idx-299008; int k=i>>7, h=i&127;
    ws[OFF_WTT + i] = W_t[h*128 + k];
  } else if (idx < 331776){
    int i = idx-315392; int k=i>>7, h=i&127;
    ws[OFF_WONET + i] = W_one[h*128 + k];
  } else if (idx < 364544){
    int i = idx-331776; int k=i>>7, h=i&127;   // k<256
    ws[OFF_WTRT + i] = W_tr[h*256 + k];
  }
}

// ---- ein/eout = hidden @ W^T + b  (2 rows/block, 400 blocks) ----
__global__ void __launch_bounds__(256) k_einout(const float* __restrict__ b_ein,
                         const float* __restrict__ b_eout, float* __restrict__ ws){
  __shared__ float hl[256];
  int t = threadIdx.x;
  int r0 = blockIdx.x * 2;
  hl[t] = ws[OFF_HID + r0*128 + t];
  __syncthreads();
  int h = t & 127;
  const float* wT = ws + ((t<128) ? OFF_WEINT : OFF_WEOUTT);
  float bias = ((t<128)? b_ein : b_eout)[h];
  float a0 = bias, a1 = bias;
  for (int k=0;k<128;k+=4){
    float w0 = wT[(k+0)*128+h], w1 = wT[(k+1)*128+h];
    float w2 = wT[(k+2)*128+h], w3 = wT[(k+3)*128+h];
    float4 h0 = *(const float4*)(hl + k);
    float4 h1 = *(const float4*)(hl + 128 + k);
    a0 += h0.x*w0 + h0.y*w1 + h0.z*w2 + h0.w*w3;
    a1 += h1.x*w0 + h1.y*w1 + h1.z*w2 + h1.w*w3;
  }
  float* dst = ws + ((t<128) ? OFF_EIN : OFF_EOUT);
  dst[(r0+0)*128 + h] = a0;
  dst[(r0+1)*128 + h] = a1;
}

// ---- fused GNN cell: 384 thr, single j-pass, 4 rows/block, grid (13,16) ----
__global__ void __launch_bounds__(384) k_cell(const float* __restrict__ A,
                       const float* __restrict__ b_iah, const float* __restrict__ b_oah,
                       const float* __restrict__ b_ih, const float* __restrict__ b_hh,
                       float* __restrict__ ws){
  __shared__ float hidr[4][128];
  __shared__ float arow[4][104];
  __shared__ float inp[4][256];
  __shared__ float gil[4][384];
  __shared__ float ghl[4][384];
  int t = threadIdx.x;
  int tile = blockIdx.x, b = blockIdx.y;
  int n0 = tile*4;
  for (int o=t; o<512; o+=384){
    int r=o>>7, h=o&127, row=n0+r;
    hidr[r][h] = (row<NN) ? ws[OFF_HID + (b*NN+row)*128 + h] : 0.0f;
  }
  for (int o=t; o<416; o+=384){
    int r=o/104, c=o-r*104;
    arow[r][c] = (c<100 && n0+r<NN) ? A[(size_t)(b*NN+n0+r)*100 + c] : 0.0f;
  }
  __syncthreads();
  for (int o=t; o<1024; o+=384){
    int r = o>>8, c8 = o&255;
    int half = (c8 < 128) ? 1 : 0;
    int c = c8 & 127;
    int row = n0 + r;
    float acc = 0.0f;
    if (row < NN){
      acc = half ? b_iah[c] : b_oah[c];
      const float* src = ws + (half?OFF_EIN:OFF_EOUT) + b*6400 + c;
      const float* ar = &arow[r][half?0:50];
      #pragma unroll 5
      for (int m=0;m<50;m++) acc += ar[m] * src[m*128];
    }
    inp[r][c8] = acc;
  }
  __syncthreads();
  {
    int j = t;
    float gi[4], gh[4];
    float bi = b_ih[j], bh = b_hh[j];
    #pragma unroll
    for (int r=0;r<4;r++){ gi[r]=bi; gh[r]=bh; }
    const float* wti = ws + OFF_WIHT;
    const float* wth = ws + OFF_WHHT;
    for (int k=0;k<256;k+=4){
      float w0 = wti[(k+0)*384+j], w1 = wti[(k+1)*384+j];
      float w2 = wti[(k+2)*384+j], w3_ = wti[(k+3)*384+j];
      #pragma unroll
      for (int r=0;r<4;r++){
        float4 iv = *(const float4*)(&inp[r][k]);
        gi[r] += iv.x*w0 + iv.y*w1 + iv.z*w2 + iv.w*w3_;
      }
    }
    for (int k=0;k<128;k+=4){
      float w0 = wth[(k+0)*384+j], w1 = wth[(k+1)*384+j];
      float w2 = wth[(k+2)*384+j], w3_ = wth[(k+3)*384+j];
      #pragma unroll
      for (int r=0;r<4;r++){
        float4 hv = *(const float4*)(&hidr[r][k]);
        gh[r] += hv.x*w0 + hv.y*w1 + hv.z*w2 + hv.w*w3_;
      }
    }
    #pragma unroll
    for (int r=0;r<4;r++){ gil[r][j]=gi[r]; ghl[r][j]=gh[r]; }
  }
  __syncthreads();
  for (int o=t; o<512; o+=384){
    int r=o>>7, h=o&127, row=n0+r;
    if (row<NN){
      float ir_=gil[r][h], ii=gil[r][128+h], inw=gil[r][256+h];
      float hr_=ghl[r][h], hi=ghl[r][128+h], hn=ghl[r][256+h];
      float rg=sigm(ir_+hr_), ig=sigm(ii+hi), ng=tanhf(inw+rg*hn);
      float hv=hidr[r][h];
      ws[OFF_HID + (b*NN+row)*128 + h] = ng + ig*(hv-ng);
    }
  }
}

// ---- merged tail: qt->frags (0..99) | pad frags (100..147) | fused attention (148..163) ----
__global__ void __launch_bounds__(256) k_tail(const int* __restrict__ mask,
                      const float* __restrict__ b_two, const float* __restrict__ b_one,
                      const float* __restrict__ w_three, const float* __restrict__ b_tr,
                      float* __restrict__ ws){
  __shared__ float hl[1024];       // qt section
  __shared__ float hidL[6400];     // attn section
  __shared__ float q2l[NN*129];
  __shared__ float q1l[128], w3l[128], htl[128], al[128], alg[64], parts[256];
  __shared__ int slen_s;
  int bx = blockIdx.x, t = threadIdx.x;
  u16* qtbf = (u16*)(ws + OFF_QTBF);
  if (bx < 100){
    // qt = (hid*mask) @ W_t^T -> bf16 fragments, 8 rows/block
    int r0 = bx * 8;
    for (int i=0;i<4;i++) hl[t+i*256] = ws[OFF_HID + r0*128 + t + i*256];
    __syncthreads();
    int h = t & 127, g = t >> 7;
    const float* wT = ws + OFF_WTT;
    float acc[4];
    #pragma unroll
    for (int r=0;r<4;r++) acc[r] = 0.0f;
    for (int k4=0;k4<32;k4++){
      int k = k4*4;
      float w0 = wT[(k+0)*128+h], w1 = wT[(k+1)*128+h];
      float w2 = wT[(k+2)*128+h], w3 = wT[(k+3)*128+h];
      #pragma unroll
      for (int r=0;r<4;r++){
        float4 hv = *(const float4*)(hl + (g*4+r)*128 + k);
        acc[r] += hv.x*w0 + hv.y*w1 + hv.z*w2 + hv.w*w3;
      }
    }
    #pragma unroll
    for (int r=0;r<4;r++){
      int row = r0 + g*4 + r;
      float val = mask[row] ? acc[r] : 0.0f;
      int b = row/NN, n = row - b*NN;
      qtbf[frag_idx(b, n, h)] = f2b(val);
    }
  } else if (bx < 148){
    // zero pad rows n=52..63
    int i = (bx-100)*256 + t;
    #pragma unroll
    for (int kk=0;kk<2;kk++){
      int e = i*2 + kk;
      int b = e/1536, rem = e - b*1536;
      int kc = rem/384, rem2 = rem - kc*384;
      int quad = rem2/96, vv = rem2 - quad*96;
      int vlo = 4 + vv/8, j = vv & 7;
      qtbf[(((b*4+3)*4+kc)<<9) + ((quad<<4)+vlo)*8 + j] = 0;
    }
  } else {
    // fused attention for batch b
    int b = bx - 148;
    for (int o=t; o<6400; o+=256) hidL[o] = ws[OFF_HID + b*6400 + o];
    if (t == 0){
      int len = 0;
      for (int n=0;n<NN;n++) len += mask[b*NN+n];
      if (len<1) len=1; if (len>NN) len=NN;
      slen_s = len;
      ((int*)(ws+OFF_LEN))[b] = len;
    }
    __syncthreads();
    int len = slen_s;
    if (t < 128){
      htl[t] = hidL[(len-1)*128 + t];
      w3l[t] = w_three[t];
    }
    __syncthreads();
    // q1 (t<128) and q2 (all threads)
    if (t < 128){
      const float* w1T = ws + OFF_WONET;
      float q1 = b_one[t];
      for (int k=0;k<128;k++) q1 += htl[k] * w1T[k*128 + t];
      q1l[t] = q1;
    }
    {
      int c = t & 127, g = t >> 7;
      const float* w2T = ws + OFF_WTWOT;
      float bt2 = b_two[c];
      for (int m=g; m<NN; m+=2){
        float acc = bt2;
        const float* hr = hidL + m*128;
        for (int k=0;k<128;k+=4){
          float4 hv = *(const float4*)(hr + k);
          acc += hv.x*w2T[(k+0)*128+c] + hv.y*w2T[(k+1)*128+c]
               + hv.z*w2T[(k+2)*128+c] + hv.w*w2T[(k+3)*128+c];
        }
        q2l[m*129 + c] = acc;
      }
    }
    __syncthreads();
    if (t < 200){
      int r = t>>2, p = t&3;
      float s = 0.0f;
      const float* qr = q2l + r*129;
      for (int h=p*32; h<p*32+32; h++) s += w3l[h]*sigm(q1l[h]+qr[h]);
      parts[t] = s;
    }
    __syncthreads();
    if (t < NN) alg[t] = parts[t*4]+parts[t*4+1]+parts[t*4+2]+parts[t*4+3];
    __syncthreads();
    if (t == 0){
      float mx = -1e30f;
      for (int n=0;n<len;n++) mx = fmaxf(mx, alg[n]);
      float ssum = 0.0f;
      for (int n=0;n<len;n++){ float e=__expf(alg[n]-mx); alg[n]=e; ssum+=e; }
      float inv = (ssum>0.0f)?1.0f/ssum:0.0f;
      for (int n=0;n<len;n++) alg[n]*=inv;
    }
    __syncthreads();
    if (t < 128){
      float a = 0.0f;
      for (int n=0;n<len;n++) a += alg[n]*hidL[n*128+t];
      al[t] = a;
    }
    __syncthreads();
    if (t < 128){
      const float* wtr = ws + OFF_WTRT;
      float af = b_tr[t];
      for (int k=0;k<128;k++) af += al[k]  * wtr[k*128 + t];
      for (int k=0;k<128;k++) af += htl[k] * wtr[(128+k)*128 + t];
      u16 hi = f2b(af);
      u16 lo = f2b(af - b2f(hi));
      qtbf[frag_idx(b, 50, t)] = hi;
      qtbf[frag_idx(b, 51, t)] = lo;
    }
  }
}

// ---- MFMA scores: LDS-staged fragments; grid (4,625): x=b-group (L2 emb reuse), y=v-chunk ----
__global__ void __launch_bounds__(256) k_scores(const float* __restrict__ emb,
                                                const float* __restrict__ ws,
                                                float* __restrict__ out){
  __shared__ u16 qlds[8192];   // 16 KB = one b's fragment block
  int tid = threadIdx.x;
  int lane = tid & 63, wave = tid >> 6;
  int quad = lane >> 4, vlo = lane & 15;
  int v = blockIdx.y*64 + wave*16 + vlo;
  int vc = (v < VO) ? v : (VO-1);
  const float* erow = emb + (size_t)(vc+1)*128;
  short8 bfr[4];
  #pragma unroll
  for (int kc=0;kc<4;kc++){
    const float4* p = (const float4*)(erow + kc*32 + quad*8);
    float4 x = p[0], y = p[1];
    union { short8 s; u32 w[4]; } u;
    u.w[0] = (u32)f2b(x.x) | ((u32)f2b(x.y)<<16);
    u.w[1] = (u32)f2b(x.z) | ((u32)f2b(x.w)<<16);
    u.w[2] = (u32)f2b(y.x) | ((u32)f2b(y.y)<<16);
    u.w[3] = (u32)f2b(y.z) | ((u32)f2b(y.w)<<16);
    bfr[kc] = u.s;
  }
  const u16* qtf = (const u16*)(ws + OFF_QTBF);
  const int* slen = (const int*)(ws + OFF_LEN);
  int b0 = blockIdx.x*4;
  for (int bi=0;bi<4;bi++){
    int b = b0 + bi;
    __syncthreads();
    {
      const uint4* src = (const uint4*)qtf + (size_t)b*1024;
      uint4* dst = (uint4*)qlds;
      #pragma unroll
      for (int r=0;r<4;r++) dst[tid + r*256] = src[tid + r*256];
    }
    __syncthreads();
    int len = slen[b];
    f32x4 acc0={0.f,0.f,0.f,0.f}, acc1=acc0, acc2=acc0, acc3=acc0;
    #pragma unroll
    for (int kc=0;kc<4;kc++){
      const u16* base = qlds + kc*512 + lane*8;   // tile stride 2048 u16
      short8 a0 = *(const short8*)(base + 0*2048);
      short8 a1 = *(const short8*)(base + 1*2048);
      short8 a2 = *(const short8*)(base + 2*2048);
      short8 a3 = *(const short8*)(base + 3*2048);
      acc0 = __builtin_amdgcn_mfma_f32_16x16x32_bf16(a0, bfr[kc], acc0, 0,0,0);
      acc1 = __builtin_amdgcn_mfma_f32_16x16x32_bf16(a1, bfr[kc], acc1, 0,0,0);
      acc2 = __builtin_amdgcn_mfma_f32_16x16x32_bf16(a2, bfr[kc], acc2, 0,0,0);
      acc3 = __builtin_amdgcn_mfma_f32_16x16x32_bf16(a3, bfr[kc], acc3, 0,0,0);
    }
    int nb = quad*4;
    float ss=0.f, nm=0.f;
    #pragma unroll
    for (int r=0;r<4;r++){
      { int n=nb+r;    if(n<len){ float e=__expf(acc0[r]); ss+=e; nm+=e*acc0[r]; } }
      { int n=nb+r+16; if(n<len){ float e=__expf(acc1[r]); ss+=e; nm+=e*acc1[r]; } }
      { int n=nb+r+32; if(n<len){ float e=__expf(acc2[r]); ss+=e; nm+=e*acc2[r]; } }
      { int n=nb+r+48; if(n<len){ float e=__expf(acc3[r]); ss+=e; nm+=e*acc3[r]; } }
    }
    ss += __shfl_xor(ss,16); ss += __shfl_xor(ss,32);
    nm += __shfl_xor(nm,16); nm += __shfl_xor(nm,32);
    if (quad==0 && v < VO){
      float pa = acc3[2] + acc3[3];   // n=50 (af_hi) + n=51 (af_lo)
      out[(size_t)b*VO + v] = nm/ss + pa;
    }
  }
}

extern "C" void kernel_launch(void* const* d_in, const int* in_sizes, int n_in,
                              void* d_out, int out_size, void* d_ws, size_t ws_size,
                              hipStream_t stream){
  const int*   items  = (const int*)d_in[0];
  const float* A      = (const float*)d_in[1];
  const int*   mask   = (const int*)d_in[2];
  const float* emb    = (const float*)d_in[3];
  const float* w_ih   = (const float*)d_in[4];
  const float* w_hh   = (const float*)d_in[5];
  const float* b_ih   = (const float*)d_in[6];
  const float* b_hh   = (const float*)d_in[7];
  const float* b_iah  = (const float*)d_in[8];
  const float* b_oah  = (const float*)d_in[9];
  const float* W_ein  = (const float*)d_in[10];
  const float* b_ein  = (const float*)d_in[11];
  const float* W_eout = (const float*)d_in[12];
  const float* b_eout = (const float*)d_in[13];
  const float* W_one  = (const float*)d_in[14];
  const float* b_one  = (const float*)d_in[15];
  const float* W_two  = (const float*)d_in[16];
  const float* b_two  = (const float*)d_in[17];
  const float* w_three= (const float*)d_in[18];
  const float* W_tr   = (const float*)d_in[19];
  const float* b_tr   = (const float*)d_in[20];
  const float* W_t    = (const float*)d_in[21];
  float* ws  = (float*)d_ws;
  float* out = (float*)d_out;

  k_pre<<<1424,256,0,stream>>>(items,emb,w_ih,w_hh,W_ein,W_eout,W_two,W_t,W_one,W_tr,ws);
  for (int s=0;s<2;s++){
    k_einout<<<400,256,0,stream>>>(b_ein,b_eout,ws);
    k_cell  <<<dim3(13,16),384,0,stream>>>(A,b_iah,b_oah,b_ih,b_hh,ws);
  }
  k_tail<<<164,256,0,stream>>>(mask,b_two,b_one,w_three,b_tr,ws);
  k_scores<<<dim3(4,625),256,0,stream>>>(emb,ws,out);
}

// Round 12
// 219.109 us; speedup vs baseline: 1.0431x; 1.0431x over previous
//
#include <hip/hip_runtime.h>

#define BB 16
#define NN 50
#define HH 128
#define VV 40000
#define VO 39999

typedef unsigned short u16;
typedef unsigned int u32;
typedef __attribute__((ext_vector_type(8))) short short8;
typedef __attribute__((ext_vector_type(4))) float f32x4;

// ---- workspace layout (float offsets) ---- high-water 673,808 f32 = 2.70 MB
#define OFF_HID    0          // 800*128
#define OFF_EIN    102400     // 800*128 ; reused as q2 after GRU
#define OFF_Q2     102400
#define OFF_EOUT   204800     // 800*128 ; reused after GRU:
#define OFF_Q1     204800     //   16*128
#define OFF_HT     206848     //   16*128
#define OFF_QTBF   307200     // qt fragments: per b: 4tile x 4kc x 512 u16 = 16 KB
#define OFF_LEN    411648     // 16 ints
#define OFF_WIHT   411664     // 256*384 k-major
#define OFF_WHHT   509968     // 128*384
#define OFF_WEINT  559120     // 128*128
#define OFF_WEOUTT 575504
#define OFF_WTWOT  591888
#define OFF_WTT    608272
#define OFF_WONET  624656
#define OFF_WTRT   641040     // 256*128  -> ends 673808

__device__ __forceinline__ float sigm(float x){ return 1.0f/(1.0f+__expf(-x)); }
__device__ __forceinline__ float b2f(u16 u){
  union { u32 i; float f; } c; c.i = ((u32)u) << 16; return c.f;
}
__device__ __forceinline__ u16 f2b(float f){
  union { float f; u32 i; } c; c.f = f;
  u32 u = c.i;
  return (u16)((u + 0x7fffu + ((u >> 16) & 1u)) >> 16);
}
// u16 index into qt fragment store for element (b, n, k)
__device__ __forceinline__ int frag_idx(int b, int n, int k){
  int tile = n>>4, vlo = n&15, kc = k>>5, quad = (k>>3)&3, j = k&7;
  return (((b*4+tile)*4+kc)<<9) + ((quad<<4)+vlo)*8 + j;
}

// ---- merged: embedding gather + transpose all weights to k-major ----
__global__ void k_pre(const int* __restrict__ items, const float* __restrict__ emb,
                      const float* __restrict__ w_ih, const float* __restrict__ w_hh,
                      const float* __restrict__ W_ein, const float* __restrict__ W_eout,
                      const float* __restrict__ W_two, const float* __restrict__ W_t,
                      const float* __restrict__ W_one, const float* __restrict__ W_tr,
                      float* __restrict__ ws){
  int idx = blockIdx.x*256 + threadIdx.x;     // grid covers exactly 364544
  if (idx < 102400){
    int r = idx >> 7, h = idx & 127;
    ws[OFF_HID + idx] = emb[items[r]*128 + h];
  } else if (idx < 200704){
    int i = idx-102400; int k=i/384, j=i-k*384;
    ws[OFF_WIHT + i] = w_ih[j*256 + k];
  } else if (idx < 249856){
    int i = idx-200704; int k=i/384, j=i-k*384;
    ws[OFF_WHHT + i] = w_hh[j*128 + k];
  } else if (idx < 266240){
    int i = idx-249856; int k=i>>7, h=i&127;
    ws[OFF_WEINT + i] = W_ein[h*128 + k];
  } else if (idx < 282624){
    int i = idx-266240; int k=i>>7, h=i&127;
    ws[OFF_WEOUTT + i] = W_eout[h*128 + k];
  } else if (idx < 299008){
    int i = idx-282624; int k=i>>7, h=i&127;
    ws[OFF_WTWOT + i] = W_two[h*128 + k];
  } else if (idx < 315392){
    int i = idx-299008; int k=i>>7, h=i&127;
    ws[OFF_WTT + i] = W_t[h*128 + k];
  } else if (idx < 331776){
    int i = idx-315392; int k=i>>7, h=i&127;
    ws[OFF_WONET + i] = W_one[h*128 + k];
  } else if (idx < 364544){
    int i = idx-331776; int k=i>>7, h=i&127;   // k<256
    ws[OFF_WTRT + i] = W_tr[h*256 + k];
  }
}

// ---- ein/eout = hidden @ W^T + b  (2 rows/block, 400 blocks) ----
__global__ void __launch_bounds__(256) k_einout(const float* __restrict__ b_ein,
                         const float* __restrict__ b_eout, float* __restrict__ ws){
  __shared__ float hl[256];
  int t = threadIdx.x;
  int r0 = blockIdx.x * 2;
  hl[t] = ws[OFF_HID + r0*128 + t];
  __syncthreads();
  int h = t & 127;
  const float* wT = ws + ((t<128) ? OFF_WEINT : OFF_WEOUTT);
  float bias = ((t<128)? b_ein : b_eout)[h];
  float a0 = bias, a1 = bias;
  for (int k=0;k<128;k+=4){
    float w0 = wT[(k+0)*128+h], w1 = wT[(k+1)*128+h];
    float w2 = wT[(k+2)*128+h], w3 = wT[(k+3)*128+h];
    float4 h0 = *(const float4*)(hl + k);
    float4 h1 = *(const float4*)(hl + 128 + k);
    a0 += h0.x*w0 + h0.y*w1 + h0.z*w2 + h0.w*w3;
    a1 += h1.x*w0 + h1.y*w1 + h1.z*w2 + h1.w*w3;
  }
  float* dst = ws + ((t<128) ? OFF_EIN : OFF_EOUT);
  dst[(r0+0)*128 + h] = a0;
  dst[(r0+1)*128 + h] = a1;
}

// ---- fused GNN cell: 384 thr, single j-pass, 4 rows/block, grid (13,16) ----
__global__ void __launch_bounds__(384) k_cell(const float* __restrict__ A,
                       const float* __restrict__ b_iah, const float* __restrict__ b_oah,
                       const float* __restrict__ b_ih, const float* __restrict__ b_hh,
                       float* __restrict__ ws){
  __shared__ float hidr[4][128];
  __shared__ float arow[4][104];
  __shared__ float inp[4][256];
  __shared__ float gil[4][384];
  __shared__ float ghl[4][384];
  int t = threadIdx.x;
  int tile = blockIdx.x, b = blockIdx.y;
  int n0 = tile*4;
  for (int o=t; o<512; o+=384){
    int r=o>>7, h=o&127, row=n0+r;
    hidr[r][h] = (row<NN) ? ws[OFF_HID + (b*NN+row)*128 + h] : 0.0f;
  }
  for (int o=t; o<416; o+=384){
    int r=o/104, c=o-r*104;
    arow[r][c] = (c<100 && n0+r<NN) ? A[(size_t)(b*NN+n0+r)*100 + c] : 0.0f;
  }
  __syncthreads();
  for (int o=t; o<1024; o+=384){
    int r = o>>8, c8 = o&255;
    int half = (c8 < 128) ? 1 : 0;
    int c = c8 & 127;
    int row = n0 + r;
    float acc = 0.0f;
    if (row < NN){
      acc = half ? b_iah[c] : b_oah[c];
      const float* src = ws + (half?OFF_EIN:OFF_EOUT) + b*6400 + c;
      const float* ar = &arow[r][half?0:50];
      #pragma unroll 5
      for (int m=0;m<50;m++) acc += ar[m] * src[m*128];
    }
    inp[r][c8] = acc;
  }
  __syncthreads();
  {
    int j = t;
    float gi[4], gh[4];
    float bi = b_ih[j], bh = b_hh[j];
    #pragma unroll
    for (int r=0;r<4;r++){ gi[r]=bi; gh[r]=bh; }
    const float* wti = ws + OFF_WIHT;
    const float* wth = ws + OFF_WHHT;
    for (int k=0;k<256;k+=4){
      float w0 = wti[(k+0)*384+j], w1 = wti[(k+1)*384+j];
      float w2 = wti[(k+2)*384+j], w3_ = wti[(k+3)*384+j];
      #pragma unroll
      for (int r=0;r<4;r++){
        float4 iv = *(const float4*)(&inp[r][k]);
        gi[r] += iv.x*w0 + iv.y*w1 + iv.z*w2 + iv.w*w3_;
      }
    }
    for (int k=0;k<128;k+=4){
      float w0 = wth[(k+0)*384+j], w1 = wth[(k+1)*384+j];
      float w2 = wth[(k+2)*384+j], w3_ = wth[(k+3)*384+j];
      #pragma unroll
      for (int r=0;r<4;r++){
        float4 hv = *(const float4*)(&hidr[r][k]);
        gh[r] += hv.x*w0 + hv.y*w1 + hv.z*w2 + hv.w*w3_;
      }
    }
    #pragma unroll
    for (int r=0;r<4;r++){ gil[r][j]=gi[r]; ghl[r][j]=gh[r]; }
  }
  __syncthreads();
  for (int o=t; o<512; o+=384){
    int r=o>>7, h=o&127, row=n0+r;
    if (row<NN){
      float ir_=gil[r][h], ii=gil[r][128+h], inw=gil[r][256+h];
      float hr_=ghl[r][h], hi=ghl[r][128+h], hn=ghl[r][256+h];
      float rg=sigm(ir_+hr_), ig=sigm(ii+hi), ng=tanhf(inw+rg*hn);
      float hv=hidr[r][h];
      ws[OFF_HID + (b*NN+row)*128 + h] = ng + ig*(hv-ng);
    }
  }
}

// ---- merged post-GRU: q2 (0..99) | qt->frags (100..199) | pad frags (200..247) | q1/ht/len (248..263) ----
__global__ void __launch_bounds__(256) k_post(const int* __restrict__ mask,
                      const float* __restrict__ b_two, const float* __restrict__ b_one,
                      float* __restrict__ ws){
  int bx = blockIdx.x, t = threadIdx.x;
  u16* qtbf = (u16*)(ws + OFF_QTBF);
  if (bx < 200){
    bool isq2 = bx < 100;
    int r0 = (isq2 ? bx : bx-100) * 8;
    __shared__ float hl[1024];
    for (int i=0;i<4;i++) hl[t+i*256] = ws[OFF_HID + r0*128 + t + i*256];
    __syncthreads();
    int h = t & 127, g = t >> 7;
    const float* wT = ws + (isq2 ? OFF_WTWOT : OFF_WTT);
    float binit = isq2 ? b_two[h] : 0.0f;
    float acc[4];
    #pragma unroll
    for (int r=0;r<4;r++) acc[r] = binit;
    for (int k4=0;k4<32;k4++){
      int k = k4*4;
      float w0 = wT[(k+0)*128+h], w1 = wT[(k+1)*128+h];
      float w2 = wT[(k+2)*128+h], w3 = wT[(k+3)*128+h];
      #pragma unroll
      for (int r=0;r<4;r++){
        float4 hv = *(const float4*)(hl + (g*4+r)*128 + k);
        acc[r] += hv.x*w0 + hv.y*w1 + hv.z*w2 + hv.w*w3;
      }
    }
    #pragma unroll
    for (int r=0;r<4;r++){
      int row = r0 + g*4 + r;
      if (isq2) ws[OFF_Q2 + row*128 + h] = acc[r];
      else {
        float val = mask[row] ? acc[r] : 0.0f;
        int b = row/NN, n = row - b*NN;
        qtbf[frag_idx(b, n, h)] = f2b(val);
      }
    }
  } else if (bx < 248){
    int i = (bx-200)*256 + t;
    #pragma unroll
    for (int kk=0;kk<2;kk++){
      int e = i*2 + kk;
      int b = e/1536, rem = e - b*1536;
      int kc = rem/384, rem2 = rem - kc*384;
      int quad = rem2/96, vv = rem2 - quad*96;
      int vlo = 4 + vv/8, j = vv & 7;
      qtbf[(((b*4+3)*4+kc)<<9) + ((quad<<4)+vlo)*8 + j] = 0;
    }
  } else {
    __shared__ float htl[128];
    int b = bx - 248;
    if (t < 128){
      int len = 0;
      for (int n=0;n<NN;n++) len += mask[b*NN+n];
      if (len<1) len=1; if (len>NN) len=NN;
      float ht = ws[OFF_HID + (b*NN + len-1)*128 + t];
      ws[OFF_HT + b*128 + t] = ht;
      htl[t] = ht;
      if (t==0) ((int*)(ws+OFF_LEN))[b] = len;
    }
    __syncthreads();
    if (t < 128){
      const float* w1T = ws + OFF_WONET;
      float q1 = b_one[t];
      for (int k=0;k<128;k++) q1 += htl[k] * w1T[k*128 + t];
      ws[OFF_Q1 + b*128 + t] = q1;
    }
  }
}

// ---- attention: alpha logits + softmax + a + af; af -> frag rows 50/51 (bf16 hi/lo) ----
__global__ void k_attn2(const float* __restrict__ w_three, const float* __restrict__ b_tr,
                        float* __restrict__ ws){
  __shared__ float q2l[NN*129];
  __shared__ float q1l[128], w3l[128], htl[128], al[128], alg[64];
  int t = threadIdx.x;   // 128
  int b = blockIdx.x;
  for (int o=t;o<NN*128;o+=128){ int n=o>>7, h=o&127; q2l[n*129+h] = ws[OFF_Q2 + b*NN*128 + o]; }
  q1l[t] = ws[OFF_Q1 + b*128 + t];
  w3l[t] = w_three[t];
  htl[t] = ws[OFF_HT + b*128 + t];
  int len = ((const int*)(ws+OFF_LEN))[b];
  __syncthreads();
  if (t < len){
    float s = 0.0f;
    const float* qr = q2l + t*129;
    for (int h=0;h<128;h++) s += w3l[h]*sigm(q1l[h]+qr[h]);
    alg[t] = s;
  }
  __syncthreads();
  if (t == 0){
    float mx = -1e30f;
    for (int n=0;n<len;n++) mx = fmaxf(mx, alg[n]);
    float ssum = 0.0f;
    for (int n=0;n<len;n++){ float e=__expf(alg[n]-mx); alg[n]=e; ssum+=e; }
    float inv = (ssum>0.0f)?1.0f/ssum:0.0f;
    for (int n=0;n<len;n++) alg[n]*=inv;
  }
  __syncthreads();
  const float* hid = ws + OFF_HID + b*NN*128;
  float a = 0.0f;
  for (int n=0;n<len;n++) a += alg[n]*hid[n*128+t];
  al[t] = a;
  __syncthreads();
  const float* wtr = ws + OFF_WTRT;
  float af = b_tr[t];
  for (int k=0;k<128;k++) af += al[k]  * wtr[k*128 + t];
  for (int k=0;k<128;k++) af += htl[k] * wtr[(128+k)*128 + t];
  u16 hi = f2b(af);
  u16 lo = f2b(af - b2f(hi));
  u16* qtbf = (u16*)(ws + OFF_QTBF);
  qtbf[frag_idx(b, 50, t)] = hi;
  qtbf[frag_idx(b, 51, t)] = lo;
}

// ---- MFMA scores: LDS-staged fragments; grid (4,625): x=b-group (L2 emb reuse), y=v-chunk ----
__global__ void __launch_bounds__(256) k_scores(const float* __restrict__ emb,
                                                const float* __restrict__ ws,
                                                float* __restrict__ out){
  __shared__ u16 qlds[8192];   // 16 KB = one b's fragment block
  int tid = threadIdx.x;
  int lane = tid & 63, wave = tid >> 6;
  int quad = lane >> 4, vlo = lane & 15;
  int v = blockIdx.y*64 + wave*16 + vlo;
  int vc = (v < VO) ? v : (VO-1);
  const float* erow = emb + (size_t)(vc+1)*128;
  short8 bfr[4];
  #pragma unroll
  for (int kc=0;kc<4;kc++){
    const float4* p = (const float4*)(erow + kc*32 + quad*8);
    float4 x = p[0], y = p[1];
    union { short8 s; u32 w[4]; } u;
    u.w[0] = (u32)f2b(x.x) | ((u32)f2b(x.y)<<16);
    u.w[1] = (u32)f2b(x.z) | ((u32)f2b(x.w)<<16);
    u.w[2] = (u32)f2b(y.x) | ((u32)f2b(y.y)<<16);
    u.w[3] = (u32)f2b(y.z) | ((u32)f2b(y.w)<<16);
    bfr[kc] = u.s;
  }
  const u16* qtf = (const u16*)(ws + OFF_QTBF);
  const int* slen = (const int*)(ws + OFF_LEN);
  int b0 = blockIdx.x*4;
  for (int bi=0;bi<4;bi++){
    int b = b0 + bi;
    __syncthreads();
    {
      const uint4* src = (const uint4*)qtf + (size_t)b*1024;
      uint4* dst = (uint4*)qlds;
      #pragma unroll
      for (int r=0;r<4;r++) dst[tid + r*256] = src[tid + r*256];
    }
    __syncthreads();
    int len = slen[b];
    f32x4 acc0={0.f,0.f,0.f,0.f}, acc1=acc0, acc2=acc0, acc3=acc0;
    #pragma unroll
    for (int kc=0;kc<4;kc++){
      const u16* base = qlds + kc*512 + lane*8;   // tile stride 2048 u16
      short8 a0 = *(const short8*)(base + 0*2048);
      short8 a1 = *(const short8*)(base + 1*2048);
      short8 a2 = *(const short8*)(base + 2*2048);
      short8 a3 = *(const short8*)(base + 3*2048);
      acc0 = __builtin_amdgcn_mfma_f32_16x16x32_bf16(a0, bfr[kc], acc0, 0,0,0);
      acc1 = __builtin_amdgcn_mfma_f32_16x16x32_bf16(a1, bfr[kc], acc1, 0,0,0);
      acc2 = __builtin_amdgcn_mfma_f32_16x16x32_bf16(a2, bfr[kc], acc2, 0,0,0);
      acc3 = __builtin_amdgcn_mfma_f32_16x16x32_bf16(a3, bfr[kc], acc3, 0,0,0);
    }
    int nb = quad*4;
    float ss=0.f, nm=0.f;
    #pragma unroll
    for (int r=0;r<4;r++){
      { int n=nb+r;    if(n<len){ float e=__expf(acc0[r]); ss+=e; nm+=e*acc0[r]; } }
      { int n=nb+r+16; if(n<len){ float e=__expf(acc1[r]); ss+=e; nm+=e*acc1[r]; } }
      { int n=nb+r+32; if(n<len){ float e=__expf(acc2[r]); ss+=e; nm+=e*acc2[r]; } }
      { int n=nb+r+48; if(n<len){ float e=__expf(acc3[r]); ss+=e; nm+=e*acc3[r]; } }
    }
    ss += __shfl_xor(ss,16); ss += __shfl_xor(ss,32);
    nm += __shfl_xor(nm,16); nm += __shfl_xor(nm,32);
    if (quad==0 && v < VO){
      float pa = acc3[2] + acc3[3];   // n=50 (af_hi) + n=51 (af_lo)
      out[(size_t)b*VO + v] = nm/ss + pa;
    }
  }
}

extern "C" void kernel_launch(void* const* d_in, const int* in_sizes, int n_in,
                              void* d_out, int out_size, void* d_ws, size_t ws_size,
                              hipStream_t stream){
  const int*   items  = (const int*)d_in[0];
  const float* A      = (const float*)d_in[1];
  const int*   mask   = (const int*)d_in[2];
  const float* emb    = (const float*)d_in[3];
  const float* w_ih   = (const float*)d_in[4];
  const float* w_hh   = (const float*)d_in[5];
  const float* b_ih   = (const float*)d_in[6];
  const float* b_hh   = (const float*)d_in[7];
  const float* b_iah  = (const float*)d_in[8];
  const float* b_oah  = (const float*)d_in[9];
  const float* W_ein  = (const float*)d_in[10];
  const float* b_ein  = (const float*)d_in[11];
  const float* W_eout = (const float*)d_in[12];
  const float* b_eout = (const float*)d_in[13];
  const float* W_one  = (const float*)d_in[14];
  const float* b_one  = (const float*)d_in[15];
  const float* W_two  = (const float*)d_in[16];
  const float* b_two  = (const float*)d_in[17];
  const float* w_three= (const float*)d_in[18];
  const float* W_tr   = (const float*)d_in[19];
  const float* b_tr   = (const float*)d_in[20];
  const float* W_t    = (const float*)d_in[21];
  float* ws  = (float*)d_ws;
  float* out = (float*)d_out;

  k_pre<<<1424,256,0,stream>>>(items,emb,w_ih,w_hh,W_ein,W_eout,W_two,W_t,W_one,W_tr,ws);
  for (int s=0;s<2;s++){
    k_einout<<<400,256,0,stream>>>(b_ein,b_eout,ws);
    k_cell  <<<dim3(13,16),384,0,stream>>>(A,b_iah,b_oah,b_ih,b_hh,ws);
  }
  k_post <<<264,256,0,stream>>>(mask,b_two,b_one,ws);
  k_attn2<<<16,128,0,stream>>>(w_three,b_tr,ws);
  k_scores<<<dim3(4,625),256,0,stream>>>(emb,ws,out);
}